// Round 8
// baseline (521.986 us; speedup 1.0000x reference)
//
#include <hip/hip_runtime.h>

// Sort_Latent_Layer: per row of (4096, 8192) fp32, view as 512 packets of 16,
// stable-argsort packets by first element, emit packets in sorted order.
//
// v6: register-resident packets + scatter-store. Minimum-traffic dataflow:
//  - Thread t loads packet t (16 floats, 4x dwordx4, contiguous 64 B) into
//    VGPRs. Key = first float (no separate key pass).
//  - Bitonic sort of 512 packed u64 (monotonic(f32)<<16 | idx): 39 steps via
//    __shfl_xor in-wave, 6 steps via LDS exchange (proven v3/v4 core).
//  - Invert permutation via one LDS scatter (ranks[idx] = pos).
//  - Thread t nt-stores its 16 registers to out + ranks[t]*16: one full 64 B
//    line per thread, written once, L2 write-combined within the row window.
//  - HBM traffic = 128 MB read + 128 MB write. No row re-read: deletes v4's
//    L2-residency dependency (which v5 broke) and v1's LDS staging conflicts.

#define NPK 512       // packets per row
#define DIM 8192      // floats per row
#define NT  512       // threads per block

typedef float vfloat4 __attribute__((ext_vector_type(4)));

__device__ __forceinline__ unsigned long long shfl_xor_u64(unsigned long long v, int mask) {
    const int lo = __shfl_xor((int)(unsigned int)(v & 0xffffffffull), mask);
    const int hi = __shfl_xor((int)(unsigned int)(v >> 32), mask);
    return ((unsigned long long)(unsigned int)hi << 32) | (unsigned int)lo;
}

__global__ __launch_bounds__(NT, 4)
void sort_latent_kernel(const float* __restrict__ z, float* __restrict__ out) {
    __shared__ __align__(16) unsigned long long keys[NPK];  // 4 KB (sort scratch)
    __shared__ int ranks[NPK];                              // 2 KB

    const int t = threadIdx.x;
    const size_t rowoff = (size_t)blockIdx.x * DIM;
    const vfloat4* __restrict__ zin4 = (const vfloat4*)(z + rowoff);
    float* __restrict__ orow = out + rowoff;

    // ---- Load own packet into registers: 4 x 16 B, contiguous 64 B/thread.
    vfloat4 p0 = zin4[t * 4 + 0];
    vfloat4 p1 = zin4[t * 4 + 1];
    vfloat4 p2 = zin4[t * 4 + 2];
    vfloat4 p3 = zin4[t * 4 + 3];

    // ---- Pack sortable key from first element ----
    unsigned int u = __float_as_uint(p0.x);
    if (u == 0x80000000u) u = 0u;                           // -0.0 -> +0.0 (tie)
    u = (u & 0x80000000u) ? ~u : (u | 0x80000000u);         // monotonic map
    unsigned long long v = ((unsigned long long)u << 16) | (unsigned long long)t;

    // ---- Bitonic sort across 512 threads, 1 element/thread ----
#pragma unroll
    for (int kk = 1; kk <= 9; ++kk) {                      // k = 2..512
        const int k = 1 << kk;
#pragma unroll
        for (int jj = kk - 1; jj >= 0; --jj) {             // j = k/2..1
            const int j = 1 << jj;
            unsigned long long vp;
            if (j < 64) {
                vp = shfl_xor_u64(v, j);                   // in-wave, no barrier
            } else {
                __syncthreads();                           // prior reads done
                keys[t] = v;
                __syncthreads();
                vp = keys[t ^ j];
            }
            const bool take_min = (((t & k) == 0) == ((t & j) == 0));
            const bool lt = (v < vp);                      // never equal (idx unique)
            v = (take_min == lt) ? v : vp;
        }
    }

    // ---- Invert: sorted position t holds source idx; tell idx its rank.
    __syncthreads();                                       // keys[] reads done
    ranks[(int)(v & 0xffffull)] = t;
    __syncthreads();
    const int r = ranks[t];                                // my packet's dest

    // ---- Scatter-store own packet to its sorted slot: full 64 B line,
    // written exactly once, nontemporal (output never re-read).
    vfloat4* __restrict__ dst = (vfloat4*)(orow + r * 16);
    __builtin_nontemporal_store(p0, dst + 0);
    __builtin_nontemporal_store(p1, dst + 1);
    __builtin_nontemporal_store(p2, dst + 2);
    __builtin_nontemporal_store(p3, dst + 3);
}

extern "C" void kernel_launch(void* const* d_in, const int* in_sizes, int n_in,
                              void* d_out, int out_size, void* d_ws, size_t ws_size,
                              hipStream_t stream) {
    const float* z = (const float*)d_in[0];
    float* out = (float*)d_out;
    const int nrows = in_sizes[0] / DIM;   // 4096
    sort_latent_kernel<<<nrows, NT, 0, stream>>>(z, out);
}

// Round 9
// 232.117 us; speedup vs baseline: 2.2488x; 2.2488x over previous
//
#include <hip/hip_runtime.h>

// Sort_Latent_Layer: per row of (4096, 8192) fp32, view as 512 packets of 16,
// stable-argsort packets by first element, emit packets in sorted order.
//
// v7 = v4b + explicit gather MLP.
//  - v6 post-mortem: scattered 64B nt-stores caused 3.3x write amplification
//    (WRITE 131->428 MB). Stores must stream; reads may scatter. v4b dataflow
//    (L2-hot gathered reads + coalesced streaming writes) is correct.
//  - v4b compiled at VGPR=12: the interleaved gather loop serialized to ~1
//    in-flight load/wave. v7 stages explicitly: 4x srcs reads, then 4x global
//    loads into named regs, then 4x nt stores -> 4x memory-level parallelism.
//  - Everything else identical to v4b: key load doubles as L2 row prefetch
//    (one packet = one 64B line), register bitonic sort (39 shfl steps +
//    6 LDS steps), 4 blocks/CU keeps gather working set = 4 MB = one XCD L2.

#define NPK 512       // packets per row
#define DIM 8192      // floats per row
#define NT  512       // threads per block

typedef float vfloat4 __attribute__((ext_vector_type(4)));

__device__ __forceinline__ unsigned long long shfl_xor_u64(unsigned long long v, int mask) {
    const int lo = __shfl_xor((int)(unsigned int)(v & 0xffffffffull), mask);
    const int hi = __shfl_xor((int)(unsigned int)(v >> 32), mask);
    return ((unsigned long long)(unsigned int)hi << 32) | (unsigned int)lo;
}

__global__ __launch_bounds__(NT, 8)
void sort_latent_kernel(const float* __restrict__ z, float* __restrict__ out) {
    __shared__ __align__(16) unsigned long long keys[NPK];  // 4 KB (sort scratch)
    __shared__ int srcs[NPK];                               // 2 KB

    const int t = threadIdx.x;
    const size_t rowoff = (size_t)blockIdx.x * DIM;
    const float* __restrict__ zrow = z + rowoff;
    const vfloat4* __restrict__ zin4 = (const vfloat4*)zrow;
    vfloat4* __restrict__ out4 = (vfloat4*)(out + rowoff);

    // ---- Key load: one float per thread, one 64 B line per packet.
    // Doubles as the L2 prefetch of the entire row for the gather below.
    unsigned int u = __float_as_uint(zrow[t * 16]);
    if (u == 0x80000000u) u = 0u;                           // -0.0 -> +0.0 (tie)
    u = (u & 0x80000000u) ? ~u : (u | 0x80000000u);         // monotonic map
    unsigned long long v = ((unsigned long long)u << 16) | (unsigned long long)t;

    // ---- Bitonic sort across 512 threads, 1 element/thread ----
#pragma unroll
    for (int kk = 1; kk <= 9; ++kk) {                      // k = 2..512
        const int k = 1 << kk;
#pragma unroll
        for (int jj = kk - 1; jj >= 0; --jj) {             // j = k/2..1
            const int j = 1 << jj;
            unsigned long long vp;
            if (j < 64) {
                vp = shfl_xor_u64(v, j);                   // in-wave, no barrier
            } else {
                __syncthreads();                           // prior reads done
                keys[t] = v;
                __syncthreads();
                vp = keys[t ^ j];
            }
            const bool take_min = (((t & k) == 0) == ((t & j) == 0));
            const bool lt = (v < vp);                      // never equal (idx unique)
            v = (take_min == lt) ? v : vp;
        }
    }

    // thread t holds the element of sorted position t
    srcs[t] = (int)(v & 0xffffull);                        // source packet index
    __syncthreads();

    // ---- Gather from global (L2-hot), 3-phase staging for 4x MLP ----
    int src[4];
#pragma unroll
    for (int i = 0; i < 4; ++i)
        src[i] = srcs[(t + NT * i) >> 2];                  // 4-lane broadcast reads

    vfloat4 val[4];
#pragma unroll
    for (int i = 0; i < 4; ++i) {
        const int o = t + NT * i;
        val[i] = zin4[(src[i] << 2) | (o & 3)];            // 4 loads in flight
    }

#pragma unroll
    for (int i = 0; i < 4; ++i)
        __builtin_nontemporal_store(val[i], &out4[t + NT * i]);  // streaming
}

extern "C" void kernel_launch(void* const* d_in, const int* in_sizes, int n_in,
                              void* d_out, int out_size, void* d_ws, size_t ws_size,
                              hipStream_t stream) {
    const float* z = (const float*)d_in[0];
    float* out = (float*)d_out;
    const int nrows = in_sizes[0] / DIM;   // 4096
    sort_latent_kernel<<<nrows, NT, 0, stream>>>(z, out);
}